// Round 4
// baseline (629.515 us; speedup 1.0000x reference)
//
#include <hip/hip_runtime.h>
#include <cstdint>
#include <cstddef>

// Problem constants
#define B_    64
#define N_    64
#define D_    2048
#define NB_   8
#define W_    57           // N - NB + 1
#define QKVLD 6144         // q|k|v concatenated row stride (gemm1 output)
#define QKLD  4096         // q2|k2 row stride (gemm2 output)
#define SCALE_ 0.022097086912079612f  // 1/sqrt(2048)

// ---------- helpers ----------
__device__ __forceinline__ float bf2f(unsigned short u){
  union { unsigned int i; float f; } x; x.i = ((unsigned int)u) << 16; return x.f;
}
__device__ __forceinline__ unsigned short f2bf(float f){
  union { float f; unsigned int i; } x; x.f = f;
  unsigned int r = x.i + 0x7fffu + ((x.i >> 16) & 1u);
  return (unsigned short)(r >> 16);
}

// ---------- fused cast: fc (2097152 float4) + nsa wq/wk/wv (3x1048576 float4) ----------
__global__ __launch_bounds__(256) void castA(const float* __restrict__ fc,
                                             const float* __restrict__ wq,
                                             const float* __restrict__ wk,
                                             const float* __restrict__ wv,
                                             unsigned short* __restrict__ fc16,
                                             unsigned short* __restrict__ wcat){
  const int i = blockIdx.x * 256 + threadIdx.x;   // [0, 5242880)
  float4 v; ushort4* dst;
  if (i < 2097152) {
    v = ((const float4*)fc)[i];
    dst = (ushort4*)fc16 + i;
  } else {
    const int j = i - 2097152;
    const int sel = j >> 20;
    const float* s = (sel == 0) ? wq : (sel == 1) ? wk : wv;
    v = ((const float4*)s)[j & 1048575];
    dst = (ushort4*)wcat + j;
  }
  ushort4 o; o.x = f2bf(v.x); o.y = f2bf(v.y); o.z = f2bf(v.z); o.w = f2bf(v.w);
  *dst = o;
}

// ---------- cast 2 DxD fp32 weights (sa wq, wk) -> contiguous bf16 ----------
__global__ __launch_bounds__(256) void castB(const float* __restrict__ a,
                                             const float* __restrict__ b,
                                             unsigned short* __restrict__ d){
  const int i = blockIdx.x * 256 + threadIdx.x;   // [0, 2097152)
  const int sel = i >> 20;
  const float* s = (sel == 0) ? a : b;
  const float4 v = ((const float4*)s)[i & 1048575];
  ushort4 o; o.x = f2bf(v.x); o.y = f2bf(v.y); o.z = f2bf(v.z); o.w = f2bf(v.w);
  ((ushort4*)d)[i] = o;
}

// ---------- bias concats: b1 = [nbq;nbk;nbv], b2 = [sbq;sbk] ----------
__global__ __launch_bounds__(256) void bias_all(
    const float* __restrict__ nq, const float* __restrict__ nk, const float* __restrict__ nv,
    const float* __restrict__ sq, const float* __restrict__ sk,
    float* __restrict__ b1, float* __restrict__ b2){
  const int i = blockIdx.x * 256 + threadIdx.x;
  if (i >= 3 * D_) return;
  const int sel = i >> 11, off = i & 2047;
  b1[i] = (sel == 0) ? nq[off] : (sel == 1) ? nk[off] : nv[off];
  if (sel < 2) b2[i] = (sel == 0) ? sq[off] : sk[off];
}

// ---------- bf16 GEMM: C[M][N] = A[M][K] @ B[N][K]^T + bias[N]  (m97 recipe) ----------
// 1D grid, XCD swizzle: xcd=flat&7 owns col-tiles {xcd, xcd+8, ...} (perx per XCD).
typedef __attribute__((ext_vector_type(8))) short bfrag8;   // 8 bf16 = 4 VGPR
typedef __attribute__((ext_vector_type(4))) float facc4;    // 4 fp32 acc

__global__ __launch_bounds__(256, 3) void gemm_bt(
    const unsigned short* __restrict__ A,
    const unsigned short* __restrict__ Bw,
    const float* __restrict__ bias,
    unsigned short* __restrict__ C,
    int N, int K, int perx)
{
  __shared__ __align__(16) unsigned short lA[128 * 32];
  __shared__ __align__(16) unsigned short lB[128 * 32];
  const int flat = blockIdx.x;
  const int xcd = flat & 7;
  const int idx = flat >> 3;
  const int ct = xcd + 8 * (idx % perx);
  const int rt = idx / perx;
  const int t = threadIdx.x;
  const int lane = t & 63, wid = t >> 6;
  const int wm = wid >> 1, wn = wid & 1;
  const size_t rowBase = (size_t)rt * 128;
  const size_t colBase = (size_t)ct * 128;
  const int sr = lane >> 2, sg = lane & 3;     // staging: 4 lanes/row, 16B each

  const unsigned short* gA0 = A  + (rowBase + (size_t)(wid * 16 + sr)) * K + sg * 8;
  const unsigned short* gB0 = Bw + (colBase + (size_t)(wid * 16 + sr)) * K + sg * 8;
  unsigned short* lA0 = &lA[(wid * 16) * 32];  // wave-uniform LDS base
  unsigned short* lB0 = &lB[(wid * 16) * 32];

  facc4 acc[4][4];
  #pragma unroll
  for (int i = 0; i < 4; i++)
    #pragma unroll
    for (int j = 0; j < 4; j++) acc[i][j] = 0;

  const int fm = lane & 15, quad = lane >> 4;
  const unsigned short* aAddr = &lA[(wm * 64 + fm) * 32 + quad * 8];
  const unsigned short* bAddr = &lB[(wn * 64 + fm) * 32 + quad * 8];

#define STAGE(k0) do { \
    __builtin_amdgcn_global_load_lds((const __attribute__((address_space(1))) void*)(gA0 + (k0)),                 (__attribute__((address_space(3))) void*)(lA0),            16, 0, 0); \
    __builtin_amdgcn_global_load_lds((const __attribute__((address_space(1))) void*)(gA0 + (size_t)64*K + (k0)),  (__attribute__((address_space(3))) void*)(lA0 + 64*32),    16, 0, 0); \
    __builtin_amdgcn_global_load_lds((const __attribute__((address_space(1))) void*)(gB0 + (k0)),                 (__attribute__((address_space(3))) void*)(lB0),            16, 0, 0); \
    __builtin_amdgcn_global_load_lds((const __attribute__((address_space(1))) void*)(gB0 + (size_t)64*K + (k0)),  (__attribute__((address_space(3))) void*)(lB0 + 64*32),    16, 0, 0); \
  } while (0)

  STAGE(0);
  __syncthreads();
  for (int kt = 0;;) {
    bfrag8 af[4], bf[4];
    #pragma unroll
    for (int i = 0; i < 4; i++) {
      af[i] = *(const bfrag8*)(aAddr + i * 16 * 32);
      bf[i] = *(const bfrag8*)(bAddr + i * 16 * 32);
    }
    #pragma unroll
    for (int i = 0; i < 4; i++)
      #pragma unroll
      for (int j = 0; j < 4; j++)
        acc[i][j] = __builtin_amdgcn_mfma_f32_16x16x32_bf16(af[i], bf[j], acc[i][j], 0, 0, 0);
    kt += 32;
    if (kt >= K) break;
    __syncthreads();
    STAGE(kt);
    __syncthreads();
  }
#undef STAGE

  // epilogue: D row = quad*4+rr, col = lane&15 (m89/m91-verified layout)
  #pragma unroll
  for (int i = 0; i < 4; i++) {
    const size_t r0 = rowBase + wm * 64 + i * 16 + quad * 4;
    #pragma unroll
    for (int j = 0; j < 4; j++) {
      const size_t cc = colBase + wn * 64 + j * 16 + fm;
      const float bv = bias[cc];
      #pragma unroll
      for (int rr = 0; rr < 4; rr++)
        C[(r0 + rr) * (size_t)N + cc] = f2bf(acc[i][j][rr] + bv);
    }
  }
}

// ---------- MFMA scores with K-split: Spart[b][ks][64][64] = q_chunk @ k_chunk^T ----------
// q rows at qkv + (b*rowsPerBatch + r)*ld, k at column offset +2048.
__global__ __launch_bounds__(256) void scores_kernel(
    const unsigned short* __restrict__ qkv, int rowsPerBatch, int ld,
    float* __restrict__ Spart)
{
  __shared__ __align__(16) unsigned short lq[64 * 32];
  __shared__ __align__(16) unsigned short lk[64 * 32];
  const int b = blockIdx.x, ks = blockIdx.y;
  const int t = threadIdx.x, lane = t & 63, wid = t >> 6;
  const int sr = lane >> 2, sg = lane & 3;
  const unsigned short* gq = qkv + ((size_t)b * rowsPerBatch + wid * 16 + sr) * ld
                             + ks * 256 + sg * 8;
  const unsigned short* gk = gq + 2048;
  unsigned short* lq0 = &lq[(wid * 16) * 32];
  unsigned short* lk0 = &lk[(wid * 16) * 32];
  const int fm = lane & 15, quad = lane >> 4;
  const unsigned short* aAddr = &lq[(wid * 16 + fm) * 32 + quad * 8];

  facc4 acc[4];
  #pragma unroll
  for (int j = 0; j < 4; j++) acc[j] = 0;

#define STAGE2(k0) do { \
    __builtin_amdgcn_global_load_lds((const __attribute__((address_space(1))) void*)(gq + (k0)), (__attribute__((address_space(3))) void*)(lq0), 16, 0, 0); \
    __builtin_amdgcn_global_load_lds((const __attribute__((address_space(1))) void*)(gk + (k0)), (__attribute__((address_space(3))) void*)(lk0), 16, 0, 0); \
  } while (0)

  STAGE2(0);
  __syncthreads();
  for (int kk = 0;;) {
    const bfrag8 af = *(const bfrag8*)aAddr;
    #pragma unroll
    for (int j = 0; j < 4; j++) {
      const bfrag8 bf = *(const bfrag8*)(&lk[(j * 16 + fm) * 32 + quad * 8]);
      acc[j] = __builtin_amdgcn_mfma_f32_16x16x32_bf16(af, bf, acc[j], 0, 0, 0);
    }
    kk += 32;
    if (kk >= 256) break;
    __syncthreads();
    STAGE2(kk);
    __syncthreads();
  }
#undef STAGE2

  float* sp = Spart + (size_t)(b * 8 + ks) * 4096;
  const int r0 = wid * 16 + quad * 4;
  #pragma unroll
  for (int j = 0; j < 4; j++)
    #pragma unroll
    for (int rr = 0; rr < 4; rr++)
      sp[(r0 + rr) * 64 + j * 16 + fm] = acc[j][rr];
}

// ---------- NSA finisher: reduce partials + band softmax column-sums ----------
__global__ __launch_bounds__(512) void nsa_fin(const float* __restrict__ Spart,
                                               float* __restrict__ cbuf){
  __shared__ float Ss[64][65];
  const int b = blockIdx.x, t = threadIdx.x;
  const float* sp = Spart + (size_t)b * 8 * 4096;
  for (int idx = t; idx < 4096; idx += 512) {
    float s = 0.f;
    #pragma unroll
    for (int ks = 0; ks < 8; ks++) s += sp[ks * 4096 + idx];
    Ss[idx >> 6][idx & 63] = s * SCALE_;
  }
  __syncthreads();
  if (t < W_ * 8) {
    const int wi = t >> 3, jp = t & 7;
    float csum = 0.f;
    for (int ip = 0; ip < 8; ip++) {
      const float* row = &Ss[wi + ip][wi];
      float mx = row[0];
      #pragma unroll
      for (int q = 1; q < 8; q++) mx = fmaxf(mx, row[q]);
      float s = 0.f, ej = 0.f;
      #pragma unroll
      for (int q = 0; q < 8; q++) { float e = __expf(row[q] - mx); s += e; if (q == jp) ej = e; }
      csum += ej / s;
    }
    cbuf[((size_t)b * W_ + wi) * 8 + jp] = csum;
  }
}

// ---------- SA2 finisher: reduce partials + softmax column-sums c2[b][j] ----------
__global__ __launch_bounds__(512) void sa2_c2(const float* __restrict__ Spart,
                                              float* __restrict__ c2buf){
  __shared__ float Ss[64][65];
  __shared__ float rowm[64], rowsum[64];
  const int b = blockIdx.x, t = threadIdx.x;
  const float* sp = Spart + (size_t)b * 8 * 4096;
  for (int idx = t; idx < 4096; idx += 512) {
    float s = 0.f;
    #pragma unroll
    for (int ks = 0; ks < 8; ks++) s += sp[ks * 4096 + idx];
    Ss[idx >> 6][idx & 63] = s * SCALE_;
  }
  __syncthreads();
  if (t < W_) {
    float mx = -1e30f;
    for (int j = 0; j < W_; j++) mx = fmaxf(mx, Ss[t][j]);
    float s = 0.f;
    for (int j = 0; j < W_; j++) s += __expf(Ss[t][j] - mx);
    rowm[t] = mx; rowsum[t] = 1.f / s;
  }
  __syncthreads();
  if (t < W_) {
    float cs = 0.f;
    for (int i = 0; i < W_; i++) cs += __expf(Ss[i][t] - rowm[i]) * rowsum[i];
    c2buf[(size_t)b * 64 + t] = cs;
  }
}

// ---------- y[b][d] = sum_j c2[b][j] * hn[b*57+j][d]  (fp32) ----------
__global__ __launch_bounds__(256) void ycomb(const unsigned short* __restrict__ hn,
                                             const float* __restrict__ c2buf,
                                             float* __restrict__ y){
  const int b = blockIdx.y;
  const int d = blockIdx.x * 256 + threadIdx.x;
  __shared__ float c2[W_];
  if (threadIdx.x < W_) c2[threadIdx.x] = c2buf[(size_t)b * 64 + threadIdx.x];
  __syncthreads();
  const unsigned short* hrow = hn + (size_t)b * W_ * 2048 + d;
  float a = 0.f;
  for (int j = 0; j < W_; j++) a += c2[j] * bf2f(hrow[(size_t)j * 2048]);
  y[(size_t)b * 2048 + d] = a;
}

// ---------- out[b][d] = sum_k y[b][k]*swv[d][k] + (sum_j c2[b][j])*sbv[d]  (all fp32) ----------
__global__ __launch_bounds__(256) void vgemv(const float* __restrict__ y,
                                             const float* __restrict__ swv,
                                             const float* __restrict__ sbv,
                                             const float* __restrict__ c2buf,
                                             float* __restrict__ out){
  const int b = blockIdx.y;
  const int d = blockIdx.x * 256 + threadIdx.x;   // blockIdx.x in [0,8) -> xcd-aligned
  __shared__ __align__(16) float yl[2048];
  __shared__ float c2[W_];
  for (int i = threadIdx.x; i < 2048; i += 256)
    yl[i] = y[(size_t)b * 2048 + i];
  if (threadIdx.x < W_) c2[threadIdx.x] = c2buf[(size_t)b * 64 + threadIdx.x];
  __syncthreads();
  float sumc = 0.f;
  #pragma unroll
  for (int j = 0; j < W_; j++) sumc += c2[j];
  const float4* wrow = (const float4*)(swv + (size_t)d * 2048);
  const float4* yl4 = (const float4*)yl;
  float a = 0.f;
  #pragma unroll 8
  for (int k4 = 0; k4 < 512; k4++) {
    const float4 w = wrow[k4];
    const float4 yv = yl4[k4];
    a += yv.x * w.x + yv.y * w.y + yv.z * w.z + yv.w * w.w;
  }
  out[(size_t)b * 2048 + d] = a + sumc * sbv[d];
}

// ---------- h = fc @ ds_w^T (per-batch) + ds_b + nsa combine (fc in bf16) ----------
__global__ __launch_bounds__(256) void h_kernel(
    const unsigned short* __restrict__ fc16, const float* __restrict__ dsw,
    const float* __restrict__ dsb, const unsigned short* __restrict__ qkv,
    const float* __restrict__ cbuf, float* __restrict__ h)
{
  const int b = blockIdx.y;
  const int d = blockIdx.x * 256 + threadIdx.x;
  __shared__ __align__(16) float dswl[W_ * 64];
  __shared__ float dsbl[W_];
  __shared__ float cl[W_ * 8];
  for (int i = threadIdx.x; i < W_ * 64; i += 256) dswl[i] = dsw[i];
  for (int i = threadIdx.x; i < W_ * 8; i += 256) cl[i] = cbuf[(size_t)b * W_ * 8 + i];
  if (threadIdx.x < W_) dsbl[threadIdx.x] = dsb[threadIdx.x];
  __syncthreads();
  float f[64];
  #pragma unroll
  for (int n = 0; n < 64; n++) f[n] = bf2f(fc16[((size_t)b * 64 + n) * 2048 + d]);
  const unsigned short* vcol = qkv + (size_t)b * 64 * QKVLD + 4096 + d;
  float* hcol = h + (size_t)b * W_ * 2048 + d;
  for (int w = 0; w < W_; w++) {
    float acc = dsbl[w];
    const float4* dw4 = (const float4*)&dswl[w * 64];
    #pragma unroll
    for (int n4 = 0; n4 < 16; n4++) {
      const float4 dv = dw4[n4];
      acc += f[4*n4+0]*dv.x + f[4*n4+1]*dv.y + f[4*n4+2]*dv.z + f[4*n4+3]*dv.w;
    }
    float an = 0.f;
    #pragma unroll
    for (int j = 0; j < 8; j++) an += cl[w * 8 + j] * bf2f(vcol[(size_t)(w + j) * QKVLD]);
    hcol[(size_t)w * 2048] = acc + an;
  }
}

// ---------- LayerNorm + cast to bf16 (pads rows [3648,3712) with zeros) ----------
__global__ __launch_bounds__(256) void ln_kernel(
    const float* __restrict__ h, const float* __restrict__ g,
    const float* __restrict__ be, unsigned short* __restrict__ hn)
{
  const int r = blockIdx.x, t = threadIdx.x;
  unsigned short* orow = hn + (size_t)r * 2048;
  if (r >= B_ * W_) {
    for (int i = t; i < 2048; i += 256) orow[i] = 0;
    return;
  }
  const float* row = h + (size_t)r * 2048;
  const float4 v0 = ((const float4*)row)[t];
  const float4 v1 = ((const float4*)row)[t + 256];
  float s  = v0.x + v0.y + v0.z + v0.w + v1.x + v1.y + v1.z + v1.w;
  float s2 = v0.x*v0.x + v0.y*v0.y + v0.z*v0.z + v0.w*v0.w
           + v1.x*v1.x + v1.y*v1.y + v1.z*v1.z + v1.w*v1.w;
  #pragma unroll
  for (int off = 32; off >= 1; off >>= 1) { s += __shfl_down(s, off); s2 += __shfl_down(s2, off); }
  __shared__ float rs[4], rs2[4];
  if ((t & 63) == 0) { rs[t >> 6] = s; rs2[t >> 6] = s2; }
  __syncthreads();
  const float st  = rs[0] + rs[1] + rs[2] + rs[3];
  const float s2t = rs2[0] + rs2[1] + rs2[2] + rs2[3];
  const float mu  = st * (1.f / 2048.f);
  const float var = s2t * (1.f / 2048.f) - mu * mu;
  const float rstd = rsqrtf(var + 1e-5f);
  const float4 g0 = ((const float4*)g)[t],  g1 = ((const float4*)g)[t + 256];
  const float4 b0 = ((const float4*)be)[t], b1 = ((const float4*)be)[t + 256];
  ushort4 o0, o1;
  o0.x = f2bf((v0.x - mu) * rstd * g0.x + b0.x);
  o0.y = f2bf((v0.y - mu) * rstd * g0.y + b0.y);
  o0.z = f2bf((v0.z - mu) * rstd * g0.z + b0.z);
  o0.w = f2bf((v0.w - mu) * rstd * g0.w + b0.w);
  o1.x = f2bf((v1.x - mu) * rstd * g1.x + b1.x);
  o1.y = f2bf((v1.y - mu) * rstd * g1.y + b1.y);
  o1.z = f2bf((v1.z - mu) * rstd * g1.z + b1.z);
  o1.w = f2bf((v1.w - mu) * rstd * g1.w + b1.w);
  ((ushort4*)orow)[t] = o0;
  ((ushort4*)orow)[t + 256] = o1;
}

// ---------- launch ----------
extern "C" void kernel_launch(void* const* d_in, const int* in_sizes, int n_in,
                              void* d_out, int out_size, void* d_ws, size_t ws_size,
                              hipStream_t stream)
{
  const float* fc  = (const float*)d_in[0];
  const float* nwq = (const float*)d_in[1];
  const float* nbq = (const float*)d_in[2];
  const float* nwk = (const float*)d_in[3];
  const float* nbk = (const float*)d_in[4];
  const float* nwv = (const float*)d_in[5];
  const float* nbv = (const float*)d_in[6];
  const float* dsw = (const float*)d_in[7];
  const float* dsb = (const float*)d_in[8];
  const float* lng = (const float*)d_in[9];
  const float* lnb = (const float*)d_in[10];
  const float* swq = (const float*)d_in[11];
  const float* sbq = (const float*)d_in[12];
  const float* swk = (const float*)d_in[13];
  const float* sbk = (const float*)d_in[14];
  const float* swv = (const float*)d_in[15];
  const float* sbv = (const float*)d_in[16];
  (void)sbk;

  char* ws = (char*)d_ws;
  unsigned short* fc16 = (unsigned short*)(ws + 0);          // 16.8 MB
  unsigned short* wcat = (unsigned short*)(ws + 16777216);   // 25.2 MB region (phase2: [swq;swk] 16.8MB)
  float* Spart         = (float*)(ws + 16777216);            // 8.4 MB — aliases wcat (disjoint lifetime)
  float* ybuf          = (float*)(ws + 25165824);            // 512 KB — inside wcat region, after gemm2
  float* bcat1         = (float*)(ws + 41943040);            // 24 KB
  float* bcat2         = (float*)(ws + 41967616);            // 16 KB used
  unsigned short* qkv  = (unsigned short*)(ws + 41992192);   // 50.3 MB (phase2: q2|k2 30.4 MB)
  float* cbuf          = (float*)(ws + 92323840);            // 117 KB (reused: c2buf)
  float* c2buf         = (float*)(ws + 92323840);            // aliases cbuf (disjoint lifetime)
  float* hbuf          = (float*)(ws + 92440576);            // 29.9 MB
  unsigned short* hn   = (unsigned short*)(ws + 122324992);  // 15.2 MB   (total ~137.5 MB)

  // fused casts + bias concat
  castA<<<20480, 256, 0, stream>>>(fc, nwq, nwk, nwv, fc16, wcat);
  bias_all<<<24, 256, 0, stream>>>(nbq, nbk, nbv, sbq, sbk, bcat1, bcat2);

  // qkv = fc16 @ [wq;wk;wv]^T + bias   (M=4096, N=6144, K=2048), 48 col-tiles, 6/XCD
  gemm_bt<<<32 * 48, 256, 0, stream>>>(fc16, wcat, bcat1, qkv, 6144, 2048, 6);

  // NSA band scores via MFMA, K-split x8 (Spart overwrites nsa weights — gemm1 done)
  scores_kernel<<<dim3(64, 8), 256, 0, stream>>>(qkv, 64, QKVLD, Spart);
  nsa_fin<<<64, 512, 0, stream>>>(Spart, cbuf);

  // h = ds-projection + nsa combine
  h_kernel<<<dim3(8, 64), 256, 0, stream>>>(fc16, dsw, dsb, qkv, cbuf, hbuf);

  // LayerNorm -> hn (bf16, padded to 3712 rows)
  ln_kernel<<<3712, 256, 0, stream>>>(hbuf, lng, lnb, hn);

  // sa q/k weights -> wcat (Spart dead)
  castB<<<8192, 256, 0, stream>>>(swq, swk, wcat);

  // q2|k2 = hn @ [wq;wk]^T + bias  (M=3712 padded, N=4096, K=2048), 32 col-tiles, 4/XCD
  gemm_bt<<<29 * 32, 256, 0, stream>>>(hn, wcat, bcat2, qkv, 4096, 2048, 4);

  // SA2 scores via MFMA (Spart overwrites sa weights — gemm2 done).
  // Rows b*57..b*57+63: max row read 63*57+63 = 3654 < 3712, in-bounds.
  scores_kernel<<<dim3(64, 8), 256, 0, stream>>>(qkv, W_, QKLD, Spart);
  sa2_c2<<<64, 512, 0, stream>>>(Spart, c2buf);

  // y = c2^T · hn  (per batch), then out = y @ swv^T + sum(c2)*sbv  — fp32 throughout
  ycomb<<<dim3(8, 64), 256, 0, stream>>>(hn, c2buf, ybuf);
  vgemv<<<dim3(8, 64), 256, 0, stream>>>(ybuf, swv, sbv, c2buf, (float*)d_out);

  (void)in_sizes; (void)n_in; (void)out_size; (void)ws_size;
}

// Round 5
// 512.140 us; speedup vs baseline: 1.2292x; 1.2292x over previous
//
#include <hip/hip_runtime.h>
#include <cstdint>
#include <cstddef>

// Problem constants
#define B_    64
#define N_    64
#define D_    2048
#define NB_   8
#define W_    57           // N - NB + 1
#define QKVLD 6144         // q|k|v concatenated row stride (gemm1 output)
#define QKLD  4096         // q2|k2 row stride (gemm2 output)
#define SCALE_ 0.022097086912079612f  // 1/sqrt(2048)

// ---------- helpers ----------
__device__ __forceinline__ float bf2f(unsigned short u){
  union { unsigned int i; float f; } x; x.i = ((unsigned int)u) << 16; return x.f;
}
__device__ __forceinline__ unsigned short f2bf(float f){
  union { float f; unsigned int i; } x; x.f = f;
  unsigned int r = x.i + 0x7fffu + ((x.i >> 16) & 1u);
  return (unsigned short)(r >> 16);
}

// ---------- fused cast: fc (2097152 float4) + nsa wq/wk/wv (3x1048576 float4) ----------
__global__ __launch_bounds__(256) void castA(const float* __restrict__ fc,
                                             const float* __restrict__ wq,
                                             const float* __restrict__ wk,
                                             const float* __restrict__ wv,
                                             unsigned short* __restrict__ fc16,
                                             unsigned short* __restrict__ wcat){
  const int i = blockIdx.x * 256 + threadIdx.x;   // [0, 5242880)
  float4 v; ushort4* dst;
  if (i < 2097152) {
    v = ((const float4*)fc)[i];
    dst = (ushort4*)fc16 + i;
  } else {
    const int j = i - 2097152;
    const int sel = j >> 20;
    const float* s = (sel == 0) ? wq : (sel == 1) ? wk : wv;
    v = ((const float4*)s)[j & 1048575];
    dst = (ushort4*)wcat + j;
  }
  ushort4 o; o.x = f2bf(v.x); o.y = f2bf(v.y); o.z = f2bf(v.z); o.w = f2bf(v.w);
  *dst = o;
}

// ---------- cast sa weights: swq,swk -> wcat2 (contiguous), swv -> swv16 ----------
__global__ __launch_bounds__(256) void castB3(const float* __restrict__ a,
                                              const float* __restrict__ b,
                                              const float* __restrict__ c,
                                              unsigned short* __restrict__ wcat2,
                                              unsigned short* __restrict__ swv16){
  const int i = blockIdx.x * 256 + threadIdx.x;   // [0, 3145728)
  const int sel = i >> 20;
  const int j = i & 1048575;
  const float* s = (sel == 0) ? a : (sel == 1) ? b : c;
  const float4 v = ((const float4*)s)[j];
  ushort4 o; o.x = f2bf(v.x); o.y = f2bf(v.y); o.z = f2bf(v.z); o.w = f2bf(v.w);
  if (sel < 2) ((ushort4*)wcat2)[i] = o;
  else         ((ushort4*)swv16)[j] = o;
}

// ---------- bias concats: b1 = [nbq;nbk;nbv], b2 = [sbq;sbk] ----------
__global__ __launch_bounds__(256) void bias_all(
    const float* __restrict__ nq, const float* __restrict__ nk, const float* __restrict__ nv,
    const float* __restrict__ sq, const float* __restrict__ sk,
    float* __restrict__ b1, float* __restrict__ b2){
  const int i = blockIdx.x * 256 + threadIdx.x;
  if (i >= 3 * D_) return;
  const int sel = i >> 11, off = i & 2047;
  b1[i] = (sel == 0) ? nq[off] : (sel == 1) ? nk[off] : nv[off];
  if (sel < 2) b2[i] = (sel == 0) ? sq[off] : sk[off];
}

// ---------- bf16 GEMM: C[M][N] = A[M][K] @ B[N][K]^T + bias[N]  (m97 recipe) ----------
// 1D grid, XCD swizzle: xcd=flat&7 owns col-tiles {xcd, xcd+8, ...} (perx per XCD).
typedef __attribute__((ext_vector_type(8))) short bfrag8;   // 8 bf16 = 4 VGPR
typedef __attribute__((ext_vector_type(4))) float facc4;    // 4 fp32 acc

__global__ __launch_bounds__(256, 3) void gemm_bt(
    const unsigned short* __restrict__ A,
    const unsigned short* __restrict__ Bw,
    const float* __restrict__ bias,
    unsigned short* __restrict__ C,
    int N, int K, int perx)
{
  __shared__ __align__(16) unsigned short lA[128 * 32];
  __shared__ __align__(16) unsigned short lB[128 * 32];
  const int flat = blockIdx.x;
  const int xcd = flat & 7;
  const int idx = flat >> 3;
  const int ct = xcd + 8 * (idx % perx);
  const int rt = idx / perx;
  const int t = threadIdx.x;
  const int lane = t & 63, wid = t >> 6;
  const int wm = wid >> 1, wn = wid & 1;
  const size_t rowBase = (size_t)rt * 128;
  const size_t colBase = (size_t)ct * 128;
  const int sr = lane >> 2, sg = lane & 3;     // staging: 4 lanes/row, 16B each

  const unsigned short* gA0 = A  + (rowBase + (size_t)(wid * 16 + sr)) * K + sg * 8;
  const unsigned short* gB0 = Bw + (colBase + (size_t)(wid * 16 + sr)) * K + sg * 8;
  unsigned short* lA0 = &lA[(wid * 16) * 32];  // wave-uniform LDS base
  unsigned short* lB0 = &lB[(wid * 16) * 32];

  facc4 acc[4][4];
  #pragma unroll
  for (int i = 0; i < 4; i++)
    #pragma unroll
    for (int j = 0; j < 4; j++) acc[i][j] = 0;

  const int fm = lane & 15, quad = lane >> 4;
  const unsigned short* aAddr = &lA[(wm * 64 + fm) * 32 + quad * 8];
  const unsigned short* bAddr = &lB[(wn * 64 + fm) * 32 + quad * 8];

#define STAGE(k0) do { \
    __builtin_amdgcn_global_load_lds((const __attribute__((address_space(1))) void*)(gA0 + (k0)),                 (__attribute__((address_space(3))) void*)(lA0),            16, 0, 0); \
    __builtin_amdgcn_global_load_lds((const __attribute__((address_space(1))) void*)(gA0 + (size_t)64*K + (k0)),  (__attribute__((address_space(3))) void*)(lA0 + 64*32),    16, 0, 0); \
    __builtin_amdgcn_global_load_lds((const __attribute__((address_space(1))) void*)(gB0 + (k0)),                 (__attribute__((address_space(3))) void*)(lB0),            16, 0, 0); \
    __builtin_amdgcn_global_load_lds((const __attribute__((address_space(1))) void*)(gB0 + (size_t)64*K + (k0)),  (__attribute__((address_space(3))) void*)(lB0 + 64*32),    16, 0, 0); \
  } while (0)

  STAGE(0);
  __syncthreads();
  for (int kt = 0;;) {
    bfrag8 af[4], bf[4];
    #pragma unroll
    for (int i = 0; i < 4; i++) {
      af[i] = *(const bfrag8*)(aAddr + i * 16 * 32);
      bf[i] = *(const bfrag8*)(bAddr + i * 16 * 32);
    }
    #pragma unroll
    for (int i = 0; i < 4; i++)
      #pragma unroll
      for (int j = 0; j < 4; j++)
        acc[i][j] = __builtin_amdgcn_mfma_f32_16x16x32_bf16(af[i], bf[j], acc[i][j], 0, 0, 0);
    kt += 32;
    if (kt >= K) break;
    __syncthreads();
    STAGE(kt);
    __syncthreads();
  }
#undef STAGE

  // epilogue: D row = quad*4+rr, col = lane&15 (m89/m91-verified layout)
  #pragma unroll
  for (int i = 0; i < 4; i++) {
    const size_t r0 = rowBase + wm * 64 + i * 16 + quad * 4;
    #pragma unroll
    for (int j = 0; j < 4; j++) {
      const size_t cc = colBase + wn * 64 + j * 16 + fm;
      const float bv = bias[cc];
      #pragma unroll
      for (int rr = 0; rr < 4; rr++)
        C[(r0 + rr) * (size_t)N + cc] = f2bf(acc[i][j][rr] + bv);
    }
  }
}

// ---------- MFMA scores with K-split: Spart[b][ks][64][64] = q_chunk @ k_chunk^T ----------
// q rows at qkv + (b*rowsPerBatch + r)*ld, k at column offset +2048.
__global__ __launch_bounds__(256) void scores_kernel(
    const unsigned short* __restrict__ qkv, int rowsPerBatch, int ld,
    float* __restrict__ Spart)
{
  __shared__ __align__(16) unsigned short lq[64 * 32];
  __shared__ __align__(16) unsigned short lk[64 * 32];
  const int b = blockIdx.x, ks = blockIdx.y;
  const int t = threadIdx.x, lane = t & 63, wid = t >> 6;
  const int sr = lane >> 2, sg = lane & 3;
  const unsigned short* gq = qkv + ((size_t)b * rowsPerBatch + wid * 16 + sr) * ld
                             + ks * 256 + sg * 8;
  const unsigned short* gk = gq + 2048;
  unsigned short* lq0 = &lq[(wid * 16) * 32];
  unsigned short* lk0 = &lk[(wid * 16) * 32];
  const int fm = lane & 15, quad = lane >> 4;
  const unsigned short* aAddr = &lq[(wid * 16 + fm) * 32 + quad * 8];

  facc4 acc[4];
  #pragma unroll
  for (int j = 0; j < 4; j++) acc[j] = 0;

#define STAGE2(k0) do { \
    __builtin_amdgcn_global_load_lds((const __attribute__((address_space(1))) void*)(gq + (k0)), (__attribute__((address_space(3))) void*)(lq0), 16, 0, 0); \
    __builtin_amdgcn_global_load_lds((const __attribute__((address_space(1))) void*)(gk + (k0)), (__attribute__((address_space(3))) void*)(lk0), 16, 0, 0); \
  } while (0)

  STAGE2(0);
  __syncthreads();
  for (int kk = 0;;) {
    const bfrag8 af = *(const bfrag8*)aAddr;
    #pragma unroll
    for (int j = 0; j < 4; j++) {
      const bfrag8 bf = *(const bfrag8*)(&lk[(j * 16 + fm) * 32 + quad * 8]);
      acc[j] = __builtin_amdgcn_mfma_f32_16x16x32_bf16(af, bf, acc[j], 0, 0, 0);
    }
    kk += 32;
    if (kk >= 256) break;
    __syncthreads();
    STAGE2(kk);
    __syncthreads();
  }
#undef STAGE2

  float* sp = Spart + (size_t)(b * 8 + ks) * 4096;
  const int r0 = wid * 16 + quad * 4;
  #pragma unroll
  for (int j = 0; j < 4; j++)
    #pragma unroll
    for (int rr = 0; rr < 4; rr++)
      sp[(r0 + rr) * 64 + j * 16 + fm] = acc[j][rr];
}

// ---------- out-projection partials: Opart[ks][64 b][2048 d] = y16 @ swv16^T (K-chunk) ----------
__global__ __launch_bounds__(256) void outproj(
    const unsigned short* __restrict__ y16, const unsigned short* __restrict__ swv16,
    float* __restrict__ Opart)
{
  __shared__ __align__(16) unsigned short ly[64 * 32];
  __shared__ __align__(16) unsigned short lv[64 * 32];
  const int dt = blockIdx.x, ks = blockIdx.y;     // 32 d-tiles x 8 k-splits
  const int t = threadIdx.x, lane = t & 63, wid = t >> 6;
  const int sr = lane >> 2, sg = lane & 3;
  const unsigned short* gy = y16  + (size_t)(wid * 16 + sr) * 2048 + ks * 256 + sg * 8;
  const unsigned short* gv = swv16 + (size_t)(dt * 64 + wid * 16 + sr) * 2048 + ks * 256 + sg * 8;
  unsigned short* ly0 = &ly[(wid * 16) * 32];
  unsigned short* lv0 = &lv[(wid * 16) * 32];
  const int fm = lane & 15, quad = lane >> 4;
  const unsigned short* aAddr = &ly[(wid * 16 + fm) * 32 + quad * 8];

  facc4 acc[4];
  #pragma unroll
  for (int j = 0; j < 4; j++) acc[j] = 0;

#define STAGE3(k0) do { \
    __builtin_amdgcn_global_load_lds((const __attribute__((address_space(1))) void*)(gy + (k0)), (__attribute__((address_space(3))) void*)(ly0), 16, 0, 0); \
    __builtin_amdgcn_global_load_lds((const __attribute__((address_space(1))) void*)(gv + (k0)), (__attribute__((address_space(3))) void*)(lv0), 16, 0, 0); \
  } while (0)

  STAGE3(0);
  __syncthreads();
  for (int kk = 0;;) {
    const bfrag8 af = *(const bfrag8*)aAddr;
    #pragma unroll
    for (int j = 0; j < 4; j++) {
      const bfrag8 bf = *(const bfrag8*)(&lv[(j * 16 + fm) * 32 + quad * 8]);
      acc[j] = __builtin_amdgcn_mfma_f32_16x16x32_bf16(af, bf, acc[j], 0, 0, 0);
    }
    kk += 32;
    if (kk >= 256) break;
    __syncthreads();
    STAGE3(kk);
    __syncthreads();
  }
#undef STAGE3

  float* op = Opart + (size_t)ks * 131072 + (size_t)dt * 64;
  const int r0 = wid * 16 + quad * 4;   // b row
  #pragma unroll
  for (int j = 0; j < 4; j++)
    #pragma unroll
    for (int rr = 0; rr < 4; rr++)
      op[(size_t)(r0 + rr) * 2048 + j * 16 + fm] = acc[j][rr];
}

// ---------- out[b][d] = sum_ks Opart + sumc2[b]*sbv[d] ----------
__global__ __launch_bounds__(256) void outfin(const float* __restrict__ Opart,
                                              const float* __restrict__ c2buf,
                                              const float* __restrict__ sbv,
                                              float* __restrict__ out){
  const int i = blockIdx.x * 256 + threadIdx.x;   // [0, 131072)
  const int b = i >> 11, d = i & 2047;
  float s = 0.f;
  #pragma unroll
  for (int ks = 0; ks < 8; ks++) s += Opart[(size_t)ks * 131072 + i];
  out[i] = s + c2buf[(size_t)b * 64 + 63] * sbv[d];
}

// ---------- NSA finisher: reduce partials + band softmax column-sums ----------
__global__ __launch_bounds__(512) void nsa_fin(const float* __restrict__ Spart,
                                               float* __restrict__ cbuf){
  __shared__ float Ss[64][65];
  const int b = blockIdx.x, t = threadIdx.x;
  const float* sp = Spart + (size_t)b * 8 * 4096;
  for (int idx = t; idx < 4096; idx += 512) {
    float s = 0.f;
    #pragma unroll
    for (int ks = 0; ks < 8; ks++) s += sp[ks * 4096 + idx];
    Ss[idx >> 6][idx & 63] = s * SCALE_;
  }
  __syncthreads();
  if (t < W_ * 8) {
    const int wi = t >> 3, jp = t & 7;
    float csum = 0.f;
    for (int ip = 0; ip < 8; ip++) {
      const float* row = &Ss[wi + ip][wi];
      float mx = row[0];
      #pragma unroll
      for (int q = 1; q < 8; q++) mx = fmaxf(mx, row[q]);
      float s = 0.f, ej = 0.f;
      #pragma unroll
      for (int q = 0; q < 8; q++) { float e = __expf(row[q] - mx); s += e; if (q == jp) ej = e; }
      csum += ej / s;
    }
    cbuf[((size_t)b * W_ + wi) * 8 + jp] = csum;
  }
}

// ---------- SA2 finisher: reduce partials + softmax column-sums c2[b][j], sumc at slot 63 ----------
__global__ __launch_bounds__(512) void sa2_c2(const float* __restrict__ Spart,
                                              float* __restrict__ c2buf){
  __shared__ float Ss[64][65];
  __shared__ float rowm[64], rowsum[64], c2s[64];
  const int b = blockIdx.x, t = threadIdx.x;
  const float* sp = Spart + (size_t)b * 8 * 4096;
  for (int idx = t; idx < 4096; idx += 512) {
    float s = 0.f;
    #pragma unroll
    for (int ks = 0; ks < 8; ks++) s += sp[ks * 4096 + idx];
    Ss[idx >> 6][idx & 63] = s * SCALE_;
  }
  __syncthreads();
  if (t < W_) {
    float mx = -1e30f;
    for (int j = 0; j < W_; j++) mx = fmaxf(mx, Ss[t][j]);
    float s = 0.f;
    for (int j = 0; j < W_; j++) s += __expf(Ss[t][j] - mx);
    rowm[t] = mx; rowsum[t] = 1.f / s;
  }
  __syncthreads();
  if (t < W_) {
    float cs = 0.f;
    for (int i = 0; i < W_; i++) cs += __expf(Ss[i][t] - rowm[i]) * rowsum[i];
    c2s[t] = cs;
    c2buf[(size_t)b * 64 + t] = cs;
  }
  __syncthreads();
  if (t == 0) {
    float s = 0.f;
    for (int j = 0; j < W_; j++) s += c2s[j];
    c2buf[(size_t)b * 64 + 63] = s;
  }
}

// ---------- y16[b][d] = bf16( sum_j c2[b][j] * hn[b*57+j][d] ) ----------
__global__ __launch_bounds__(256) void ycomb(const unsigned short* __restrict__ hn,
                                             const float* __restrict__ c2buf,
                                             unsigned short* __restrict__ y16){
  const int b = blockIdx.y;
  const int d = blockIdx.x * 256 + threadIdx.x;
  __shared__ float c2[W_];
  if (threadIdx.x < W_) c2[threadIdx.x] = c2buf[(size_t)b * 64 + threadIdx.x];
  __syncthreads();
  const unsigned short* hrow = hn + (size_t)b * W_ * 2048 + d;
  float a = 0.f;
  for (int j = 0; j < W_; j++) a += c2[j] * bf2f(hrow[(size_t)j * 2048]);
  y16[(size_t)b * 2048 + d] = f2bf(a);
}

// ---------- h = fc @ ds_w^T (per-batch) + ds_b + nsa combine (fc in bf16) ----------
__global__ __launch_bounds__(256) void h_kernel(
    const unsigned short* __restrict__ fc16, const float* __restrict__ dsw,
    const float* __restrict__ dsb, const unsigned short* __restrict__ qkv,
    const float* __restrict__ cbuf, float* __restrict__ h)
{
  const int b = blockIdx.y;
  const int d = blockIdx.x * 256 + threadIdx.x;
  __shared__ __align__(16) float dswl[W_ * 64];
  __shared__ float dsbl[W_];
  __shared__ float cl[W_ * 8];
  for (int i = threadIdx.x; i < W_ * 64; i += 256) dswl[i] = dsw[i];
  for (int i = threadIdx.x; i < W_ * 8; i += 256) cl[i] = cbuf[(size_t)b * W_ * 8 + i];
  if (threadIdx.x < W_) dsbl[threadIdx.x] = dsb[threadIdx.x];
  __syncthreads();
  float f[64];
  #pragma unroll
  for (int n = 0; n < 64; n++) f[n] = bf2f(fc16[((size_t)b * 64 + n) * 2048 + d]);
  const unsigned short* vcol = qkv + (size_t)b * 64 * QKVLD + 4096 + d;
  float* hcol = h + (size_t)b * W_ * 2048 + d;
  for (int w = 0; w < W_; w++) {
    float acc = dsbl[w];
    const float4* dw4 = (const float4*)&dswl[w * 64];
    #pragma unroll
    for (int n4 = 0; n4 < 16; n4++) {
      const float4 dv = dw4[n4];
      acc += f[4*n4+0]*dv.x + f[4*n4+1]*dv.y + f[4*n4+2]*dv.z + f[4*n4+3]*dv.w;
    }
    float an = 0.f;
    #pragma unroll
    for (int j = 0; j < 8; j++) an += cl[w * 8 + j] * bf2f(vcol[(size_t)(w + j) * QKVLD]);
    hcol[(size_t)w * 2048] = acc + an;
  }
}

// ---------- LayerNorm + cast to bf16 (pads rows [3648,3712) with zeros) ----------
__global__ __launch_bounds__(256) void ln_kernel(
    const float* __restrict__ h, const float* __restrict__ g,
    const float* __restrict__ be, unsigned short* __restrict__ hn)
{
  const int r = blockIdx.x, t = threadIdx.x;
  unsigned short* orow = hn + (size_t)r * 2048;
  if (r >= B_ * W_) {
    for (int i = t; i < 2048; i += 256) orow[i] = 0;
    return;
  }
  const float* row = h + (size_t)r * 2048;
  const float4 v0 = ((const float4*)row)[t];
  const float4 v1 = ((const float4*)row)[t + 256];
  float s  = v0.x + v0.y + v0.z + v0.w + v1.x + v1.y + v1.z + v1.w;
  float s2 = v0.x*v0.x + v0.y*v0.y + v0.z*v0.z + v0.w*v0.w
           + v1.x*v1.x + v1.y*v1.y + v1.z*v1.z + v1.w*v1.w;
  #pragma unroll
  for (int off = 32; off >= 1; off >>= 1) { s += __shfl_down(s, off); s2 += __shfl_down(s2, off); }
  __shared__ float rs[4], rs2[4];
  if ((t & 63) == 0) { rs[t >> 6] = s; rs2[t >> 6] = s2; }
  __syncthreads();
  const float st  = rs[0] + rs[1] + rs[2] + rs[3];
  const float s2t = rs2[0] + rs2[1] + rs2[2] + rs2[3];
  const float mu  = st * (1.f / 2048.f);
  const float var = s2t * (1.f / 2048.f) - mu * mu;
  const float rstd = rsqrtf(var + 1e-5f);
  const float4 g0 = ((const float4*)g)[t],  g1 = ((const float4*)g)[t + 256];
  const float4 b0 = ((const float4*)be)[t], b1 = ((const float4*)be)[t + 256];
  ushort4 o0, o1;
  o0.x = f2bf((v0.x - mu) * rstd * g0.x + b0.x);
  o0.y = f2bf((v0.y - mu) * rstd * g0.y + b0.y);
  o0.z = f2bf((v0.z - mu) * rstd * g0.z + b0.z);
  o0.w = f2bf((v0.w - mu) * rstd * g0.w + b0.w);
  o1.x = f2bf((v1.x - mu) * rstd * g1.x + b1.x);
  o1.y = f2bf((v1.y - mu) * rstd * g1.y + b1.y);
  o1.z = f2bf((v1.z - mu) * rstd * g1.z + b1.z);
  o1.w = f2bf((v1.w - mu) * rstd * g1.w + b1.w);
  ((ushort4*)orow)[t] = o0;
  ((ushort4*)orow)[t + 256] = o1;
}

// ---------- launch ----------
extern "C" void kernel_launch(void* const* d_in, const int* in_sizes, int n_in,
                              void* d_out, int out_size, void* d_ws, size_t ws_size,
                              hipStream_t stream)
{
  const float* fc  = (const float*)d_in[0];
  const float* nwq = (const float*)d_in[1];
  const float* nbq = (const float*)d_in[2];
  const float* nwk = (const float*)d_in[3];
  const float* nbk = (const float*)d_in[4];
  const float* nwv = (const float*)d_in[5];
  const float* nbv = (const float*)d_in[6];
  const float* dsw = (const float*)d_in[7];
  const float* dsb = (const float*)d_in[8];
  const float* lng = (const float*)d_in[9];
  const float* lnb = (const float*)d_in[10];
  const float* swq = (const float*)d_in[11];
  const float* sbq = (const float*)d_in[12];
  const float* swk = (const float*)d_in[13];
  const float* sbk = (const float*)d_in[14];
  const float* swv = (const float*)d_in[15];
  const float* sbv = (const float*)d_in[16];
  (void)sbk;

  char* ws = (char*)d_ws;
  unsigned short* fc16  = (unsigned short*)(ws + 0);          // 16.8 MB
  unsigned short* wcat  = (unsigned short*)(ws + 16777216);   // 25.2 MB (nsa weights; dead after gemm1)
  float* Spart          = (float*)(ws + 16777216);            // 8.4 MB — aliases wcat head
  unsigned short* wcat2 = (unsigned short*)(ws + 25165824);   // 16.8 MB ([swq;swk]; dead after gemm2)
  float* bcat1          = (float*)(ws + 41943040);            // 24 KB
  float* bcat2          = (float*)(ws + 41967616);            // 16 KB used
  unsigned short* qkv   = (unsigned short*)(ws + 41992192);   // 50.3 MB (phase2: q2|k2 30.4 MB)
  float* cbuf           = (float*)(ws + 92323840);            // 117 KB (reused: c2buf)
  float* c2buf          = (float*)(ws + 92323840);            // aliases cbuf (disjoint lifetime)
  float* hbuf           = (float*)(ws + 92440576);            // 29.9 MB (dead after ln — reused below)
  unsigned short* swv16 = (unsigned short*)(ws + 92440576);   // 8.4 MB  — in dead hbuf
  unsigned short* y16   = (unsigned short*)(ws + 100829184);  // 256 KB  — in dead hbuf
  float* Opart          = (float*)(ws + 101091328);           // 4 MB    — in dead hbuf
  unsigned short* hn    = (unsigned short*)(ws + 122324992);  // 15.2 MB   (total ~137.5 MB)

  // fused casts + bias concat
  castA<<<20480, 256, 0, stream>>>(fc, nwq, nwk, nwv, fc16, wcat);
  bias_all<<<24, 256, 0, stream>>>(nbq, nbk, nbv, sbq, sbk, bcat1, bcat2);

  // qkv = fc16 @ [wq;wk;wv]^T + bias   (M=4096, N=6144, K=2048), 48 col-tiles, 6/XCD
  gemm_bt<<<32 * 48, 256, 0, stream>>>(fc16, wcat, bcat1, qkv, 6144, 2048, 6);

  // NSA band scores via MFMA, K-split x8 (Spart overwrites nsa weights — gemm1 done)
  scores_kernel<<<dim3(64, 8), 256, 0, stream>>>(qkv, 64, QKVLD, Spart);
  nsa_fin<<<64, 512, 0, stream>>>(Spart, cbuf);

  // h = ds-projection + nsa combine
  h_kernel<<<dim3(8, 64), 256, 0, stream>>>(fc16, dsw, dsb, qkv, cbuf, hbuf);

  // LayerNorm -> hn (bf16, padded to 3712 rows); hbuf dead afterwards
  ln_kernel<<<3712, 256, 0, stream>>>(hbuf, lng, lnb, hn);

  // sa weights: swq,swk -> wcat2, swv -> swv16 (dead-hbuf region)
  castB3<<<12288, 256, 0, stream>>>(swq, swk, swv, wcat2, swv16);

  // q2|k2 = hn @ [swq;swk]^T + bias  (M=3712 padded, N=4096, K=2048), 32 col-tiles, 4/XCD
  gemm_bt<<<29 * 32, 256, 0, stream>>>(hn, wcat2, bcat2, qkv, 4096, 2048, 4);

  // SA2 scores via MFMA (rows b*57..b*57+63; max 3654 < 3712, in-bounds)
  scores_kernel<<<dim3(64, 8), 256, 0, stream>>>(qkv, W_, QKLD, Spart);
  sa2_c2<<<64, 512, 0, stream>>>(Spart, c2buf);

  // y16 = bf16(c2^T · hn); out = y16 @ swv16^T (MFMA, K-split x8) + sumc*sbv
  ycomb<<<dim3(8, 64), 256, 0, stream>>>(hn, c2buf, y16);
  outproj<<<dim3(32, 8), 256, 0, stream>>>(y16, swv16, Opart);
  outfin<<<512, 256, 0, stream>>>(Opart, c2buf, sbv, (float*)d_out);

  (void)in_sizes; (void)n_in; (void)out_size; (void)ws_size;
}